// Round 14
// baseline (1356.593 us; speedup 1.0000x reference)
//
#include <hip/hip_runtime.h>
#include <math.h>

#define T 2048
#define D 768
#define E 8
#define FF 3072
#define NPOS (2 * T)
#define MAXTILE 40
#define PSTRIDE ((size_t)(NPOS + 128) * D)

// work queue layout
#define NR 512
#define ISCAN 512
#define W13_0 513
#define NW13 2304
#define W2_0 2817
#define NW2 1152
#define G1_0 3969
#define NG1 960
#define G2_0 4929
#define NG2 480
#define C_0 5409
#define NC 2048
#define NITEMS 7457

// counter indices
#define CQ 0
#define CR 1
#define CS 2
#define CW13 3    // +e (8)
#define CW2 11    // +e (8)
#define CG1 19    // +slot (20)
#define CG2 39
#define NCTR 40

using f32x4 = __attribute__((ext_vector_type(4))) float;

template<bool HI>
__device__ __forceinline__ unsigned f2fp8pk(float a, float b, unsigned old) {
    return __builtin_amdgcn_cvt_pk_fp8_f32(a, b, (int)old, HI);
}
__device__ __forceinline__ unsigned char f2fp8(float f) {
    return (unsigned char)(__builtin_amdgcn_cvt_pk_fp8_f32(f, 0.f, 0, false) & 0xff);
}
__device__ __forceinline__ float siluf(float v) {
    return v / (1.0f + __expf(-v));
}
__device__ __forceinline__ void gload16(const void* g, void* l) {
    __builtin_amdgcn_global_load_lds(
        (const __attribute__((address_space(1))) void*)g,
        (__attribute__((address_space(3))) void*)l, 16, 0, 0);
}

// gate: spin until ctr[idx] >= target (skip if this block already passed it)
__device__ __forceinline__ void gateGE(int* ctr, int idx, int target,
                                       unsigned long long& gmask, int tid) {
    unsigned long long bit = 1ull << idx;
    if (gmask & bit) return;
    if (tid == 0) {
        while (atomicAdd(&ctr[idx], 0) < target) __builtin_amdgcn_s_sleep(4);
    }
    __syncthreads();
    __threadfence();   // acquire: invalidate stale cache before reading produced data
    gmask |= bit;
}
// done: make this block's stores device-visible, then bump counter
__device__ __forceinline__ void doneAdd(int* ctr, int idx, int tid) {
    __syncthreads();   // drains vmcnt -> stores at L2
    __threadfence();   // release: write back L2 so other XCDs see it
    if (tid == 0) atomicAdd(&ctr[idx], 1);
}

// ---------------------------------------------------------------------------
// transpose128 (R12-verified): 128x128 f32 tile -> fp8 transposed via
// gload_lds staging (full MLP), convert+pack, 128B-line stores.
// ---------------------------------------------------------------------------
__device__ __forceinline__ void transpose128(const float* __restrict__ in,
                                             unsigned char* __restrict__ out,
                                             int C, int Rb, int r0, int c0,
                                             char* smem, int tid) {
    int wv = tid >> 6, lane = tid & 63;
    size_t rowB = (size_t)C * 4;
    const char* inb = (const char*)in + (size_t)r0 * rowB + (size_t)c0 * 4;
    const char* src_lane = inb + (size_t)(lane >> 5) * rowB + (lane & 31) * 16;
#pragma unroll
    for (int i = 0; i < 16; ++i) {
        int rpair = i * 4 + wv;
        gload16(src_lane + (size_t)(2 * rpair) * rowB, smem + rpair * 1024);
    }
    asm volatile("s_waitcnt vmcnt(0)" ::: "memory");
    __syncthreads();

    const float* fin = (const float*)smem;
    int cb = (tid & 31) * 4;
    int rgb = tid >> 5;
    unsigned pk[4][4];
#pragma unroll
    for (int p = 0; p < 4; ++p) {
        int rb = (rgb + 8 * p) * 4;
        float4 q0 = *(const float4*)(fin + (rb + 0) * 128 + cb);
        float4 q1 = *(const float4*)(fin + (rb + 1) * 128 + cb);
        float4 q2 = *(const float4*)(fin + (rb + 2) * 128 + cb);
        float4 q3 = *(const float4*)(fin + (rb + 3) * 128 + cb);
        unsigned w;
        w = f2fp8pk<false>(q0.x, q1.x, 0); w = f2fp8pk<true>(q2.x, q3.x, w); pk[p][0] = w;
        w = f2fp8pk<false>(q0.y, q1.y, 0); w = f2fp8pk<true>(q2.y, q3.y, w); pk[p][1] = w;
        w = f2fp8pk<false>(q0.z, q1.z, 0); w = f2fp8pk<true>(q2.z, q3.z, w); pk[p][2] = w;
        w = f2fp8pk<false>(q0.w, q1.w, 0); w = f2fp8pk<true>(q2.w, q3.w, w); pk[p][3] = w;
    }
    __syncthreads();
    unsigned* po = (unsigned*)smem;    // [128 cols][33 words]
#pragma unroll
    for (int p = 0; p < 4; ++p) {
        int rg = rgb + 8 * p;
#pragma unroll
        for (int j = 0; j < 4; ++j)
            po[(cb + j) * 33 + rg] = pk[p][j];
    }
    __syncthreads();
#pragma unroll
    for (int p = 0; p < 4; ++p) {
        int c = (tid >> 3) + 32 * p;
        int gs = tid & 7;
        const unsigned* bp = &po[c * 33 + gs * 4];
        uint4 val;
        val.x = bp[0]; val.y = bp[1]; val.z = bp[2]; val.w = bp[3];
        *(uint4*)(out + (size_t)(c0 + c) * Rb + r0 + gs * 16) = val;
    }
}

// ---------------------------------------------------------------------------
// THE mega-kernel: persistent blocks, global work queue, gated phases
// ---------------------------------------------------------------------------
__global__ __launch_bounds__(256, 2)
void moe_mega(const float* __restrict__ x,
              const float* __restrict__ rw, const float* __restrict__ rbias,
              const float* __restrict__ dgw, const float* __restrict__ dgb,
              const float* __restrict__ w1, const float* __restrict__ w1b,
              const float* __restrict__ w2, const float* __restrict__ w2b,
              const float* __restrict__ w3, const float* __restrict__ w3b,
              const float* __restrict__ lng, const float* __restrict__ lnb,
              unsigned char* __restrict__ xb,
              int* __restrict__ e_arr, float* __restrict__ s_arr,
              int* __restrict__ a_tok, int* __restrict__ pos_of,
              int* __restrict__ tme, int* __restrict__ tmm, int* __restrict__ tml,
              unsigned char* __restrict__ w1t, unsigned char* __restrict__ w3t,
              unsigned char* __restrict__ w2t,
              unsigned char* __restrict__ acts, float* __restrict__ ffs,
              float* __restrict__ out, float* __restrict__ load_out,
              int* __restrict__ ctr) {
    __shared__ __align__(16) char smem[73728];
    __shared__ int curit;
    int tid = threadIdx.x;
    unsigned long long gmask = 0;

    for (;;) {
        if (tid == 0) curit = atomicAdd(&ctr[CQ], 1);
        __syncthreads();
        int item = curit;
        if (item >= NITEMS) return;

        if (item < NR) {
            // ================= ROUTER (4 tokens, one per wave) ==============
            int lane = tid & 63;
            int wv = tid >> 6;
            int t = item * 4 + wv;

            float lg[E], dl[E];
#pragma unroll
            for (int e = 0; e < E; ++e) { lg[e] = 0.f; dl[e] = 0.f; }
            const float* xt = x + (size_t)t * D;
            unsigned char* xbt = xb + (size_t)t * D;
#pragma unroll
            for (int i = 0; i < D / 64; ++i) {
                int d = lane + 64 * i;
                float xv = xt[d];
                xbt[d] = f2fp8(xv);
#pragma unroll
                for (int e = 0; e < E; ++e) {
                    lg[e] = fmaf(xv, rw[d * E + e], lg[e]);
                    dl[e] = fmaf(xv, dgw[e * D + d], dl[e]);
                }
            }
#pragma unroll
            for (int e = 0; e < E; ++e) {
                for (int off = 32; off; off >>= 1) {
                    lg[e] += __shfl_xor(lg[e], off);
                    dl[e] += __shfl_xor(dl[e], off);
                }
            }
            if (lane == 0) {
                float p[E];
                float m = -1e30f;
#pragma unroll
                for (int e = 0; e < E; ++e) { lg[e] += rbias[e]; m = fmaxf(m, lg[e]); }
                float s = 0.f;
#pragma unroll
                for (int e = 0; e < E; ++e) { p[e] = __expf(lg[e] - m); s += p[e]; }
                float inv = 1.0f / s;
#pragma unroll
                for (int e = 0; e < E; ++e) p[e] *= inv;
                int i0 = 0; float b0 = p[0];
#pragma unroll
                for (int e = 1; e < E; ++e) if (p[e] > b0) { b0 = p[e]; i0 = e; }
                int i1 = -1; float b1 = -1.0f;
#pragma unroll
                for (int e = 0; e < E; ++e) if (e != i0 && p[e] > b1) { b1 = p[e]; i1 = e; }
                float eb = __expf(b1 - b0);
                float w0 = 1.0f / (1.0f + eb);
                float w1v = eb / (1.0f + eb);
                float dg0 = 1.0f / (1.0f + __expf(-(dl[i0] + dgb[i0])));
                float dg1 = 1.0f / (1.0f + __expf(-(dl[i1] + dgb[i1])));
                e_arr[t * 2 + 0] = i0;
                e_arr[t * 2 + 1] = i1;
                s_arr[t * 2 + 0] = dg0 * w0;
                s_arr[t * 2 + 1] = dg1 * w1v;
            }
            doneAdd(ctr, CR, tid);

        } else if (item == ISCAN) {
            // ================= SCAN + ASSIGN (single item) ==================
            gateGE(ctr, CR, NR, gmask, tid);
            int* lcnt = (int*)smem;
            int* lcur = lcnt + E;
            if (tid < E) lcnt[tid] = 0;
            __syncthreads();
            for (int t = tid; t < T; t += 256) {
                atomicAdd(&lcnt[e_arr[t * 2]], 1);
                atomicAdd(&lcnt[e_arr[t * 2 + 1]], 1);
            }
            __syncthreads();
            if (tid == 0) {
                int b = 0, nt = 0;
                for (int e = 0; e < E; ++e) {
                    int c = lcnt[e];
                    lcur[e] = b;
                    load_out[e] = (float)c;
                    for (int m = 0; m < c; m += 128) {
                        tme[nt] = e;
                        tmm[nt] = b + m;
                        tml[nt] = (c - m < 128) ? (c - m) : 128;
                        ++nt;
                    }
                    b += c;
                }
                for (; nt < MAXTILE; ++nt) tme[nt] = -1;
            }
            __syncthreads();
            for (int t = tid; t < T; t += 256) {
#pragma unroll
                for (int s = 0; s < 2; ++s) {
                    int e = e_arr[t * 2 + s];
                    int pos = atomicAdd(&lcur[e], 1);
                    a_tok[pos] = t;
                    pos_of[t * 2 + s] = pos;
                }
            }
            doneAdd(ctr, CS, tid);

        } else if (item < W2_0) {
            // ================= w1/w3 TRANSPOSE (expert-major) ===============
            int i = item - W13_0;
            int e = i / 288;
            int sub = i % 288;
            int z = (sub < 144) ? e : (8 + e);
            int tile = sub % 144;
            int r0 = (tile % 6) * 128;
            int c0 = (tile / 6) * 128;
            const float* in;
            unsigned char* outp;
            if (z < 8) { in = w1 + (size_t)z * D * FF; outp = w1t + (size_t)z * D * FF; }
            else       { in = w3 + (size_t)(z - 8) * D * FF; outp = w3t + (size_t)(z - 8) * D * FF; }
            transpose128(in, outp, FF, D, r0, c0, smem, tid);
            doneAdd(ctr, CW13 + e, tid);

        } else if (item < G1_0) {
            // ================= w2 TRANSPOSE (expert-major) ==================
            int i = item - W2_0;
            int e = i / 144;
            int tile = i % 144;
            int r0 = (tile % 24) * 128;
            int c0 = (tile / 24) * 128;
            transpose128(w2 + (size_t)e * FF * D, w2t + (size_t)e * FF * D,
                         D, FF, r0, c0, smem, tid);
            doneAdd(ctr, CW2 + e, tid);

        } else if (item < G2_0) {
            // ================= GEMM1 (persistent 2-M-tile) ==================
            int i = item - G1_0;
            int slot = i / 48;
            int fBase = (i % 48) * 64;
            gateGE(ctr, CS, 1, gmask, tid);
            int mt0 = slot * 2;
            int e0 = tme[mt0];
            if (e0 < 0) { doneAdd(ctr, CG1 + slot, tid); continue; }
            int e1 = tme[mt0 + 1];
            bool have2 = (e1 >= 0);
            int mstart0 = tmm[mt0], mlen0 = tml[mt0];
            int mstart1 = have2 ? tmm[mt0 + 1] : mstart0;
            int mlen1   = have2 ? tml[mt0 + 1] : mlen0;
            if (!have2) e1 = e0;
            gateGE(ctr, CW13 + e0, 288, gmask, tid);
            gateGE(ctr, CW13 + e1, 288, gmask, tid);

            char* As = smem;              // 2 x 16KB
            char* Bs = smem + 32768;      // 2 x 16KB
            unsigned char* eplds = (unsigned char*)(smem + 65536);  // 8KB

            int lane = tid & 63, wv = tid >> 6;
            int wr = wv & 1, wc = wv >> 1;
            int l15 = lane & 15, lk = lane >> 4;
            int lrow = lane >> 3;
            int swl = (((lane & 7) ^ lrow) << 4);

            const char* xbp = (const char*)xb;
            const char* w1p0 = (const char*)(w1t + (size_t)e0 * FF * D);
            const char* w3p0 = (const char*)(w3t + (size_t)e0 * FF * D);
            const char* w1p1 = (const char*)(w1t + (size_t)e1 * FF * D);
            const char* w3p1 = (const char*)(w3t + (size_t)e1 * FF * D);

            size_t boff[2];
#pragma unroll
            for (int k = 0; k < 2; ++k) {
                int f = (wv + 4 * k) * 8 + lrow;
                boff[k] = (size_t)(fBase + f) * D + swl;
            }
            size_t a0[4], a1[4];
#pragma unroll
            for (int k = 0; k < 4; ++k) {
                int r = (wv + 4 * k) * 8 + lrow;
                int rr0 = r < mlen0 ? r : mlen0 - 1;
                int rr1 = r < mlen1 ? r : mlen1 - 1;
                a0[k] = (size_t)a_tok[mstart0 + rr0] * D + swl;
                a1[k] = (size_t)a_tok[mstart1 + rr1] * D + swl;
            }
            float tb1[2][2], tb3[2][2];
#pragma unroll
            for (int n = 0; n < 2; ++n) {
                int f = fBase + wc * 32 + n * 16 + l15;
                tb1[0][n] = w1b[e0 * FF + f];
                tb3[0][n] = w3b[e0 * FF + f];
                tb1[1][n] = w1b[e1 * FF + f];
                tb3[1][n] = w3b[e1 * FF + f];
            }

            auto stage = [&](int buf, const size_t* ao, const char* w1p_,
                             const char* w3p_, int ks) {
                int kb = ks * 128;
                char* ab = As + buf * 16384;
                char* bb = Bs + buf * 16384;
#pragma unroll
                for (int k = 0; k < 4; ++k)
                    gload16(xbp + ao[k] + kb, ab + (wv + 4 * k) * 1024);
#pragma unroll
                for (int k = 0; k < 2; ++k) {
                    gload16(w1p_ + boff[k] + kb, bb + (wv + 4 * k) * 1024);
                    gload16(w3p_ + boff[k] + kb, bb + 8192 + (wv + 4 * k) * 1024);
                }
            };

            f32x4 hacc[4][2], gacc[4][2];
            auto zacc = [&]() {
#pragma unroll
                for (int m = 0; m < 4; ++m)
#pragma unroll
                    for (int n = 0; n < 2; ++n) {
                        hacc[m][n] = f32x4{0.f, 0.f, 0.f, 0.f};
                        gacc[m][n] = f32x4{0.f, 0.f, 0.f, 0.f};
                    }
            };
            auto computeStep = [&](int buf) {
                const char* Ab = As + buf * 16384;
                const char* Bb = Bs + buf * 16384;
                __builtin_amdgcn_s_setprio(1);
#pragma unroll
                for (int ksub = 0; ksub < 4; ++ksub) {
                    int koff = ksub * 32 + lk * 8;
                    long af[4];
#pragma unroll
                    for (int m = 0; m < 4; ++m) {
                        int row = wr * 64 + m * 16 + l15;
                        af[m] = *(const long*)(Ab + row * 128 + (koff ^ ((row & 7) << 4)));
                    }
#pragma unroll
                    for (int n = 0; n < 2; ++n) {
                        int rowf = wc * 32 + n * 16 + l15;
                        int off = rowf * 128 + (koff ^ ((rowf & 7) << 4));
                        long b1 = *(const long*)(Bb + off);
                        long b3 = *(const long*)(Bb + 8192 + off);
#pragma unroll
                        for (int m = 0; m < 4; ++m) {
                            hacc[m][n] = __builtin_amdgcn_mfma_f32_16x16x32_fp8_fp8(af[m], b1, hacc[m][n], 0, 0, 0);
                            gacc[m][n] = __builtin_amdgcn_mfma_f32_16x16x32_fp8_fp8(af[m], b3, gacc[m][n], 0, 0, 0);
                        }
                    }
                }
                __builtin_amdgcn_s_setprio(0);
            };
            auto epilogueT = [&](const float b1v[2], const float b3v[2],
                                 int mstart_, int mlen_) {
#pragma unroll
                for (int m = 0; m < 4; ++m)
#pragma unroll
                    for (int n = 0; n < 2; ++n)
#pragma unroll
                        for (int j = 0; j < 4; ++j) {
                            float h = hacc[m][n][j] + b1v[n];
                            float gg = gacc[m][n][j] + b3v[n];
                            int row = wr * 64 + m * 16 + lk * 4 + j;
                            int col = wc * 32 + n * 16 + l15;
                            eplds[row * 64 + col] = f2fp8(siluf(h) * siluf(gg));
                        }
                __syncthreads();
                int r = tid >> 1, cb = (tid & 1) * 32;
                if (r < mlen_) {
                    unsigned char* gp = acts + (size_t)(mstart_ + r) * FF + fBase + cb;
                    const unsigned char* lp = eplds + r * 64 + cb;
                    *(uint4*)(gp)      = *(const uint4*)(lp);
                    *(uint4*)(gp + 16) = *(const uint4*)(lp + 16);
                }
            };

#define G1_WAIT8 asm volatile("s_waitcnt vmcnt(8)" ::: "memory")
#define G1_BAR   __builtin_amdgcn_s_barrier()
            zacc();
            stage(0, a0, w1p0, w3p0, 0);
            stage(1, a0, w1p0, w3p0, 1);
            asm volatile("s_waitcnt vmcnt(0)" ::: "memory");
            __syncthreads();
            /*s0*/ computeStep(0); G1_BAR; stage(0, a0, w1p0, w3p0, 2);
            /*s1*/ G1_BAR; computeStep(1); G1_BAR; stage(1, a0, w1p0, w3p0, 3);
            /*s2*/ G1_WAIT8; G1_BAR; computeStep(0); G1_BAR; stage(0, a0, w1p0, w3p0, 4);
            /*s3*/ G1_WAIT8; G1_BAR; computeStep(1); G1_BAR; stage(1, a0, w1p0, w3p0, 5);
            /*s4*/ G1_WAIT8; G1_BAR; computeStep(0); G1_BAR; stage(0, a1, w1p1, w3p1, 0);
            /*s5*/ G1_WAIT8; G1_BAR; computeStep(1); G1_BAR; stage(1, a1, w1p1, w3p1, 1);
            epilogueT(tb1[0], tb3[0], mstart0, mlen0);
            asm volatile("s_waitcnt vmcnt(0)" ::: "memory");
            __syncthreads();
            if (have2) {
                zacc();
                /*s0*/ computeStep(0); G1_BAR; stage(0, a1, w1p1, w3p1, 2);
                /*s1*/ G1_BAR; computeStep(1); G1_BAR; stage(1, a1, w1p1, w3p1, 3);
                /*s2*/ G1_WAIT8; G1_BAR; computeStep(0); G1_BAR; stage(0, a1, w1p1, w3p1, 4);
                /*s3*/ G1_WAIT8; G1_BAR; computeStep(1); G1_BAR; stage(1, a1, w1p1, w3p1, 5);
                /*s4*/ G1_WAIT8; G1_BAR; computeStep(0); G1_BAR;
                /*s5*/ asm volatile("s_waitcnt vmcnt(0)" ::: "memory"); G1_BAR; computeStep(1); G1_BAR;
                epilogueT(tb1[1], tb3[1], mstart1, mlen1);
            }
#undef G1_WAIT8
#undef G1_BAR
            doneAdd(ctr, CG1 + slot, tid);

        } else if (item < C_0) {
            // ================= GEMM2 (128x128, split-K=2) ===================
            int i = item - G2_0;
            int mt = i / 12;
            int rem = i % 12;
            int nBase = (rem >> 1) * 128;
            int ksl = rem & 1;
            gateGE(ctr, CG1 + (mt >> 1), 48, gmask, tid);
            int e = tme[mt];
            if (e < 0) { doneAdd(ctr, CG2, tid); continue; }
            gateGE(ctr, CW2 + e, 144, gmask, tid);
            int mstart = tmm[mt], mlen = tml[mt];

            char (*As)[16384] = (char(*)[16384])smem;
            char (*Bs)[16384] = (char(*)[16384])(smem + 32768);

            int lane = tid & 63, wv = tid >> 6;
            int wr = wv & 1, wc = wv >> 1;
            int l15 = lane & 15, lk = lane >> 4;
            int lrow = lane >> 3;
            int swl = (((lane & 7) ^ lrow) << 4);

            const char* ap = (const char*)acts;
            const char* w2p = (const char*)(w2t + (size_t)e * (size_t)D * FF);
            size_t aoff[4], boff[4];
#pragma unroll
            for (int k = 0; k < 4; ++k) {
                int r = (wv + 4 * k) * 8 + lrow;
                aoff[k] = (size_t)(mstart + r) * FF + swl;
                boff[k] = (size_t)(nBase + r) * FF + swl;
            }
            int kOff = ksl * (FF / 2);

            auto stage2 = [&](int buf, int ks) {
                int kb = kOff + ks * 128;
                char* ab = &As[buf][0];
                char* bb = &Bs[buf][0];
#pragma unroll
                for (int k = 0; k < 4; ++k) {
                    gload16(ap + aoff[k] + kb, ab + (wv + 4 * k) * 1024);
                    gload16(w2p + boff[k] + kb, bb + (wv + 4 * k) * 1024);
                }
            };

            f32x4 facc[4][4];
#pragma unroll
            for (int m = 0; m < 4; ++m)
#pragma unroll
                for (int n = 0; n < 4; ++n) facc[m][n] = f32x4{0.f, 0.f, 0.f, 0.f};

            stage2(0, 0);
            stage2(1, 1);
#pragma unroll 1
            for (int ks = 0; ks < 12; ++ks) {
                int cur = ks & 1;
                if (ks < 11) asm volatile("s_waitcnt vmcnt(8)" ::: "memory");
                else         asm volatile("s_waitcnt vmcnt(0)" ::: "memory");
                __builtin_amdgcn_s_barrier();
                const char* Ab = &As[cur][0];
                const char* Bb = &Bs[cur][0];
                __builtin_amdgcn_s_setprio(1);
#pragma unroll
                for (int ksub = 0; ksub < 4; ++ksub) {
                    int koff = ksub * 32 + lk * 8;
                    long af[4], bf[4];
#pragma unroll
                    for (int m = 0; m < 4; ++m) {
                        int row = wr * 64 + m * 16 + l15;
                        af[m] = *(const long*)(Ab + row * 128 + (koff ^ ((row & 7) << 4)));
                    }
#pragma unroll
                    for (int n = 0; n < 4; ++n) {
                        int row = wc * 64 + n * 16 + l15;
                        bf[n] = *(const long*)(Bb + row * 128 + (koff ^ ((row & 7) << 4)));
                    }
#pragma unroll
                    for (int m = 0; m < 4; ++m)
#pragma unroll
                        for (int n = 0; n < 4; ++n)
                            facc[m][n] = __builtin_amdgcn_mfma_f32_16x16x32_fp8_fp8(af[m], bf[n], facc[m][n], 0, 0, 0);
                }
                __builtin_amdgcn_s_setprio(0);
                __builtin_amdgcn_s_barrier();
                if (ks < 10) stage2(cur, ks + 2);
            }

            float* op = ffs + (size_t)ksl * PSTRIDE;
#pragma unroll
            for (int m = 0; m < 4; ++m)
#pragma unroll
                for (int j = 0; j < 4; ++j) {
                    int row = wr * 64 + m * 16 + lk * 4 + j;
                    if (row < mlen) {
                        float* gp = op + (size_t)(mstart + row) * D + nBase + wc * 64;
#pragma unroll
                        for (int n = 0; n < 4; ++n)
                            gp[n * 16 + l15] = facc[m][n][j];
                    }
                }
            doneAdd(ctr, CG2, tid);

        } else {
            // ================= COMBINE (one token) ==========================
            int t = item - C_0;
            gateGE(ctr, CG2, NG2, gmask, tid);
            float* red = (float*)smem;   // [4][4]
            int p0 = pos_of[t * 2], p1 = pos_of[t * 2 + 1];
            int e0 = e_arr[t * 2], e1 = e_arr[t * 2 + 1];
            float sw0 = s_arr[t * 2], sw1 = s_arr[t * 2 + 1];

            float y0[3], y1[3];
            float s0 = 0.f, q0 = 0.f, s1 = 0.f, q1 = 0.f;
#pragma unroll
            for (int m = 0; m < 3; ++m) {
                int d = tid + 256 * m;
                float xv = x[(size_t)t * D + d];
                float f0 = ffs[(size_t)p0 * D + d] + ffs[PSTRIDE + (size_t)p0 * D + d] + w2b[e0 * D + d];
                float f1 = ffs[(size_t)p1 * D + d] + ffs[PSTRIDE + (size_t)p1 * D + d] + w2b[e1 * D + d];
                float a = xv + sw0 * f0;
                float bb = xv + sw1 * f1;
                y0[m] = a; y1[m] = bb;
                s0 += a; q0 += a * a;
                s1 += bb; q1 += bb * bb;
            }
            for (int off = 32; off; off >>= 1) {
                s0 += __shfl_xor(s0, off);
                q0 += __shfl_xor(q0, off);
                s1 += __shfl_xor(s1, off);
                q1 += __shfl_xor(q1, off);
            }
            int wv = tid >> 6, lane = tid & 63;
            if (lane == 0) { red[wv * 4 + 0] = s0; red[wv * 4 + 1] = q0; red[wv * 4 + 2] = s1; red[wv * 4 + 3] = q1; }
            __syncthreads();
            s0 = red[0] + red[4] + red[8] + red[12];
            q0 = red[1] + red[5] + red[9] + red[13];
            s1 = red[2] + red[6] + red[10] + red[14];
            q1 = red[3] + red[7] + red[11] + red[15];

            const float invD = 1.0f / (float)D;
            float mu0 = s0 * invD, var0 = q0 * invD - mu0 * mu0;
            float mu1 = s1 * invD, var1 = q1 * invD - mu1 * mu1;
            float r0 = rsqrtf(var0 + 1e-5f);
            float r1 = rsqrtf(var1 + 1e-5f);
#pragma unroll
            for (int m = 0; m < 3; ++m) {
                int d = tid + 256 * m;
                out[(size_t)t * D + d] =
                    (y0[m] - mu0) * r0 * lng[e0 * D + d] + lnb[e0 * D + d] +
                    (y1[m] - mu1) * r1 * lng[e1 * D + d] + lnb[e1 * D + d];
            }
            __syncthreads();   // protect smem (red) before next item
        }
    }
}

// ---------------------------------------------------------------------------
extern "C" void kernel_launch(void* const* d_in, const int* in_sizes, int n_in,
                              void* d_out, int out_size, void* d_ws, size_t ws_size,
                              hipStream_t stream) {
    const float* x   = (const float*)d_in[0];
    const float* rw  = (const float*)d_in[1];
    const float* rb  = (const float*)d_in[2];
    const float* dgw = (const float*)d_in[3];
    const float* dgb = (const float*)d_in[4];
    const float* w1  = (const float*)d_in[5];
    const float* w1b = (const float*)d_in[6];
    const float* w2  = (const float*)d_in[7];
    const float* w2b = (const float*)d_in[8];
    const float* w3  = (const float*)d_in[9];
    const float* w3b = (const float*)d_in[10];
    const float* lng = (const float*)d_in[11];
    const float* lnb = (const float*)d_in[12];

    float* out = (float*)d_out;
    float* load_out = out + (size_t)T * D;

    char* w = (char*)d_ws;
    size_t off = 0;
    auto alloc = [&](size_t bytes) -> void* {
        void* p = w + off;
        off = (off + bytes + 255) & ~(size_t)255;
        return p;
    };
    int* ctr      = (int*)alloc(NCTR * sizeof(int));
    int* e_arr    = (int*)alloc(NPOS * sizeof(int));
    int* a_tok    = (int*)alloc(NPOS * sizeof(int));
    int* pos_of   = (int*)alloc(NPOS * sizeof(int));
    float* s_arr  = (float*)alloc(NPOS * sizeof(float));
    int* tme      = (int*)alloc(MAXTILE * sizeof(int));
    int* tmm      = (int*)alloc(MAXTILE * sizeof(int));
    int* tml      = (int*)alloc(MAXTILE * sizeof(int));
    unsigned char* xb  = (unsigned char*)alloc((size_t)T * D);
    unsigned char* w1t = (unsigned char*)alloc((size_t)E * D * FF);
    unsigned char* w3t = (unsigned char*)alloc((size_t)E * D * FF);
    unsigned char* w2t = (unsigned char*)alloc((size_t)E * D * FF);
    unsigned char* acts = (unsigned char*)alloc((size_t)(NPOS + 128) * FF);
    float* ffs    = (float*)alloc(2 * PSTRIDE * sizeof(float));

    (void)hipMemsetAsync(ctr, 0, NCTR * sizeof(int), stream);
    moe_mega<<<512, 256, 0, stream>>>(x, rw, rb, dgw, dgb, w1, w1b, w2, w2b,
                                      w3, w3b, lng, lnb,
                                      xb, e_arr, s_arr, a_tok, pos_of,
                                      tme, tmm, tml, w1t, w3t, w2t,
                                      acts, ffs, out, load_out, ctr);
}

// Round 15
// 149.911 us; speedup vs baseline: 9.0493x; 9.0493x over previous
//
#include <hip/hip_runtime.h>
#include <math.h>

#define T 2048
#define D 768
#define E 8
#define FF 3072
#define NPOS (2 * T)
#define MAXTILE 40
#define PSTRIDE ((size_t)(NPOS + 128) * D)

using f32x4 = __attribute__((ext_vector_type(4))) float;

template<bool HI>
__device__ __forceinline__ unsigned f2fp8pk(float a, float b, unsigned old) {
    return __builtin_amdgcn_cvt_pk_fp8_f32(a, b, (int)old, HI);
}
__device__ __forceinline__ unsigned char f2fp8(float f) {
    return (unsigned char)(__builtin_amdgcn_cvt_pk_fp8_f32(f, 0.f, 0, false) & 0xff);
}
__device__ __forceinline__ float siluf(float v) {
    return v / (1.0f + __expf(-v));
}
__device__ __forceinline__ void gload16(const void* g, void* l) {
    __builtin_amdgcn_global_load_lds(
        (const __attribute__((address_space(1))) void*)g,
        (__attribute__((address_space(3))) void*)l, 16, 0, 0);
}

// ---------------------------------------------------------------------------
// transpose128 (R12-verified, best-measured): 128x128 f32 tile -> fp8
// transposed via gload_lds staging (full MLP), convert+pack, 128B-line stores.
// ---------------------------------------------------------------------------
__device__ __forceinline__ void transpose128(const float* __restrict__ in,
                                             unsigned char* __restrict__ out,
                                             int C, int Rb, int r0, int c0,
                                             char* smem, int tid) {
    int wv = tid >> 6, lane = tid & 63;
    size_t rowB = (size_t)C * 4;
    const char* inb = (const char*)in + (size_t)r0 * rowB + (size_t)c0 * 4;
    const char* src_lane = inb + (size_t)(lane >> 5) * rowB + (lane & 31) * 16;
#pragma unroll
    for (int i = 0; i < 16; ++i) {
        int rpair = i * 4 + wv;
        gload16(src_lane + (size_t)(2 * rpair) * rowB, smem + rpair * 1024);
    }
    asm volatile("s_waitcnt vmcnt(0)" ::: "memory");
    __syncthreads();

    const float* fin = (const float*)smem;
    int cb = (tid & 31) * 4;
    int rgb = tid >> 5;
    unsigned pk[4][4];
#pragma unroll
    for (int p = 0; p < 4; ++p) {
        int rb = (rgb + 8 * p) * 4;
        float4 q0 = *(const float4*)(fin + (rb + 0) * 128 + cb);
        float4 q1 = *(const float4*)(fin + (rb + 1) * 128 + cb);
        float4 q2 = *(const float4*)(fin + (rb + 2) * 128 + cb);
        float4 q3 = *(const float4*)(fin + (rb + 3) * 128 + cb);
        unsigned w;
        w = f2fp8pk<false>(q0.x, q1.x, 0); w = f2fp8pk<true>(q2.x, q3.x, w); pk[p][0] = w;
        w = f2fp8pk<false>(q0.y, q1.y, 0); w = f2fp8pk<true>(q2.y, q3.y, w); pk[p][1] = w;
        w = f2fp8pk<false>(q0.z, q1.z, 0); w = f2fp8pk<true>(q2.z, q3.z, w); pk[p][2] = w;
        w = f2fp8pk<false>(q0.w, q1.w, 0); w = f2fp8pk<true>(q2.w, q3.w, w); pk[p][3] = w;
    }
    __syncthreads();
    unsigned* po = (unsigned*)smem;    // [128 cols][33 words]
#pragma unroll
    for (int p = 0; p < 4; ++p) {
        int rg = rgb + 8 * p;
#pragma unroll
        for (int j = 0; j < 4; ++j)
            po[(cb + j) * 33 + rg] = pk[p][j];
    }
    __syncthreads();
#pragma unroll
    for (int p = 0; p < 4; ++p) {
        int c = (tid >> 3) + 32 * p;
        int gs = tid & 7;
        const unsigned* bp = &po[c * 33 + gs * 4];
        uint4 val;
        val.x = bp[0]; val.y = bp[1]; val.z = bp[2]; val.w = bp[3];
        *(uint4*)(out + (size_t)(c0 + c) * Rb + r0 + gs * 16) = val;
    }
}

// ---------------------------------------------------------------------------
// Dispatch 1: router (512) + w1/w3 transpose (2304), interleaved 2:9
// (2816 = 256 groups x 11 -> every resident wave-set mixes both flavors)
// ---------------------------------------------------------------------------
__global__ __launch_bounds__(256, 2)
void pre_kernel(const float* __restrict__ x,
                const float* __restrict__ rw, const float* __restrict__ rbias,
                const float* __restrict__ dgw, const float* __restrict__ dgb,
                const float* __restrict__ w1, const float* __restrict__ w3,
                unsigned char* __restrict__ xb,
                int* __restrict__ e_arr, float* __restrict__ s_arr,
                unsigned char* __restrict__ w1t, unsigned char* __restrict__ w3t) {
    __shared__ __align__(16) char smem[73728];
    int bid = blockIdx.x;
    int tid = threadIdx.x;
    int grp = bid / 11, rem = bid % 11;

    if (rem >= 2) {
        // ---- w1/w3 transpose flavor ----
        int idx = grp * 9 + (rem - 2);    // 0..2303
        int z = idx / 144;
        int tile = idx % 144;
        int r0 = (tile % 6) * 128;
        int c0 = (tile / 6) * 128;
        const float* in;
        unsigned char* outp;
        if (z < 8) { in = w1 + (size_t)z * D * FF; outp = w1t + (size_t)z * D * FF; }
        else       { in = w3 + (size_t)(z - 8) * D * FF; outp = w3t + (size_t)(z - 8) * D * FF; }
        transpose128(in, outp, FF, D, r0, c0, smem, tid);
        return;
    }

    // ---- router flavor ----
    int rblk = grp * 2 + rem;             // 0..511
    int lane = tid & 63;
    int wv = tid >> 6;
    int t = rblk * 4 + wv;

    float lg[E], dl[E];
#pragma unroll
    for (int e = 0; e < E; ++e) { lg[e] = 0.f; dl[e] = 0.f; }

    const float* xt = x + (size_t)t * D;
    unsigned char* xbt = xb + (size_t)t * D;
#pragma unroll
    for (int i = 0; i < D / 64; ++i) {
        int d = lane + 64 * i;
        float xv = xt[d];
        xbt[d] = f2fp8(xv);
#pragma unroll
        for (int e = 0; e < E; ++e) {
            lg[e] = fmaf(xv, rw[d * E + e], lg[e]);
            dl[e] = fmaf(xv, dgw[e * D + d], dl[e]);
        }
    }
#pragma unroll
    for (int e = 0; e < E; ++e) {
        for (int off = 32; off; off >>= 1) {
            lg[e] += __shfl_xor(lg[e], off);
            dl[e] += __shfl_xor(dl[e], off);
        }
    }
    if (lane == 0) {
        float p[E];
        float m = -1e30f;
#pragma unroll
        for (int e = 0; e < E; ++e) { lg[e] += rbias[e]; m = fmaxf(m, lg[e]); }
        float s = 0.f;
#pragma unroll
        for (int e = 0; e < E; ++e) { p[e] = __expf(lg[e] - m); s += p[e]; }
        float inv = 1.0f / s;
#pragma unroll
        for (int e = 0; e < E; ++e) p[e] *= inv;

        int i0 = 0; float b0 = p[0];
#pragma unroll
        for (int e = 1; e < E; ++e) if (p[e] > b0) { b0 = p[e]; i0 = e; }
        int i1 = -1; float b1 = -1.0f;
#pragma unroll
        for (int e = 0; e < E; ++e) if (e != i0 && p[e] > b1) { b1 = p[e]; i1 = e; }

        float eb = __expf(b1 - b0);
        float w0 = 1.0f / (1.0f + eb);
        float w1v = eb / (1.0f + eb);

        float dg0 = 1.0f / (1.0f + __expf(-(dl[i0] + dgb[i0])));
        float dg1 = 1.0f / (1.0f + __expf(-(dl[i1] + dgb[i1])));

        e_arr[t * 2 + 0] = i0;
        e_arr[t * 2 + 1] = i1;
        s_arr[t * 2 + 0] = dg0 * w0;
        s_arr[t * 2 + 1] = dg1 * w1v;
    }
}

// ---------------------------------------------------------------------------
// Dispatch 2: scan+assign (counts in-LDS)
// ---------------------------------------------------------------------------
__global__ __launch_bounds__(256)
void scan_assign_kernel(const int* __restrict__ e_arr,
                        float* __restrict__ load_out,
                        int* __restrict__ tme, int* __restrict__ tmm,
                        int* __restrict__ tml,
                        int* __restrict__ a_tok,
                        int* __restrict__ pos_of) {
    __shared__ int lcnt[E];
    __shared__ int lcur[E];
    int tid = threadIdx.x;
    if (tid < E) lcnt[tid] = 0;
    __syncthreads();
    for (int t = tid; t < T; t += 256) {
        atomicAdd(&lcnt[e_arr[t * 2]], 1);
        atomicAdd(&lcnt[e_arr[t * 2 + 1]], 1);
    }
    __syncthreads();
    if (tid == 0) {
        int b = 0, nt = 0;
        for (int e = 0; e < E; ++e) {
            int c = lcnt[e];
            lcur[e] = b;
            load_out[e] = (float)c;
            for (int m = 0; m < c; m += 128) {
                tme[nt] = e;
                tmm[nt] = b + m;
                tml[nt] = (c - m < 128) ? (c - m) : 128;
                ++nt;
            }
            b += c;
        }
        for (; nt < MAXTILE; ++nt) tme[nt] = -1;
    }
    __syncthreads();
    for (int t = tid; t < T; t += 256) {
#pragma unroll
        for (int s = 0; s < 2; ++s) {
            int e = e_arr[t * 2 + s];
            int pos = atomicAdd(&lcur[e], 1);
            a_tok[pos] = t;
            pos_of[t * 2 + s] = pos;
        }
    }
}

// ---------------------------------------------------------------------------
// Dispatch 3: GEMM1 (960) + w2 transpose (1152), interleaved 5:6
// (2112 = 192 groups x 11). GEMM1: persistent 2-M-tile pipeline, 128x64,
// BK=128, counted vmcnt, setprio.
// ---------------------------------------------------------------------------
__global__ __launch_bounds__(256, 2)
void gemm1_w2t_kernel(const float* __restrict__ w2, unsigned char* __restrict__ w2t,
                      const unsigned char* __restrict__ xb,
                      const unsigned char* __restrict__ w1t, const float* __restrict__ w1b,
                      const unsigned char* __restrict__ w3t, const float* __restrict__ w3b,
                      const int* __restrict__ a_tok,
                      const int* __restrict__ tme, const int* __restrict__ tmm,
                      const int* __restrict__ tml,
                      unsigned char* __restrict__ acts) {
    __shared__ __align__(16) char smem[73728];
    int bid = blockIdx.x;
    int tid = threadIdx.x;
    int grp = bid / 11, rem = bid % 11;

    if (rem >= 5) {   // ---- w2 transpose flavor (6 per group) ----
        int idx = grp * 6 + (rem - 5);    // 0..1151
        int z = idx / 144;
        int tile = idx % 144;
        int r0 = (tile % 24) * 128;
        int c0 = (tile / 24) * 128;
        transpose128(w2 + (size_t)z * FF * D, w2t + (size_t)z * FF * D,
                     D, FF, r0, c0, smem, tid);
        return;
    }

    // ---- gemm1 persistent flavor (5 per group) ----
    int g = grp * 5 + rem;                // 0..959
    int slot = g / 48;
    int fBase = (g % 48) * 64;
    int mt0 = slot * 2;
    int e0 = tme[mt0];
    if (e0 < 0) return;
    int e1 = tme[mt0 + 1];
    bool have2 = (e1 >= 0);
    int mstart0 = tmm[mt0], mlen0 = tml[mt0];
    int mstart1 = have2 ? tmm[mt0 + 1] : mstart0;
    int mlen1   = have2 ? tml[mt0 + 1] : mlen0;
    if (!have2) e1 = e0;

    char* As = smem;              // 2 x 16KB
    char* Bs = smem + 32768;      // 2 x 16KB
    unsigned char* eplds = (unsigned char*)(smem + 65536);  // 8KB

    int lane = tid & 63, wv = tid >> 6;
    int wr = wv & 1, wc = wv >> 1;
    int l15 = lane & 15, lk = lane >> 4;
    int lrow = lane >> 3;
    int swl = (((lane & 7) ^ lrow) << 4);

    const char* xbp = (const char*)xb;
    const char* w1p0 = (const char*)(w1t + (size_t)e0 * FF * D);
    const char* w3p0 = (const char*)(w3t + (size_t)e0 * FF * D);
    const char* w1p1 = (const char*)(w1t + (size_t)e1 * FF * D);
    const char* w3p1 = (const char*)(w3t + (size_t)e1 * FF * D);

    size_t boff[2];
#pragma unroll
    for (int i = 0; i < 2; ++i) {
        int f = (wv + 4 * i) * 8 + lrow;
        boff[i] = (size_t)(fBase + f) * D + swl;
    }

    size_t a0[4], a1[4];
#pragma unroll
    for (int i = 0; i < 4; ++i) {
        int r = (wv + 4 * i) * 8 + lrow;
        int rr0 = r < mlen0 ? r : mlen0 - 1;
        int rr1 = r < mlen1 ? r : mlen1 - 1;
        a0[i] = (size_t)a_tok[mstart0 + rr0] * D + swl;
        a1[i] = (size_t)a_tok[mstart1 + rr1] * D + swl;
    }
    float tb1[2][2], tb3[2][2];
#pragma unroll
    for (int n = 0; n < 2; ++n) {
        int f = fBase + wc * 32 + n * 16 + l15;
        tb1[0][n] = w1b[e0 * FF + f];
        tb3[0][n] = w3b[e0 * FF + f];
        tb1[1][n] = w1b[e1 * FF + f];
        tb3[1][n] = w3b[e1 * FF + f];
    }

    auto stage = [&](int buf, const size_t* ao, const char* w1p_, const char* w3p_, int ks) {
        int kb = ks * 128;
        char* ab = As + buf * 16384;
        char* bb = Bs + buf * 16384;
#pragma unroll
        for (int i = 0; i < 4; ++i)
            gload16(xbp + ao[i] + kb, ab + (wv + 4 * i) * 1024);
#pragma unroll
        for (int i = 0; i < 2; ++i) {
            gload16(w1p_ + boff[i] + kb, bb + (wv + 4 * i) * 1024);
            gload16(w3p_ + boff[i] + kb, bb + 8192 + (wv + 4 * i) * 1024);
        }
    };

    f32x4 hacc[4][2], gacc[4][2];
    auto zacc = [&]() {
#pragma unroll
        for (int m = 0; m < 4; ++m)
#pragma unroll
            for (int n = 0; n < 2; ++n) {
                hacc[m][n] = f32x4{0.f, 0.f, 0.f, 0.f};
                gacc[m][n] = f32x4{0.f, 0.f, 0.f, 0.f};
            }
    };

    auto computeStep = [&](int buf) {
        const char* Ab = As + buf * 16384;
        const char* Bb = Bs + buf * 16384;
        __builtin_amdgcn_s_setprio(1);
#pragma unroll
        for (int ksub = 0; ksub < 4; ++ksub) {
            int koff = ksub * 32 + lk * 8;
            long af[4];
#pragma unroll
            for (int m = 0; m < 4; ++m) {
                int row = wr * 64 + m * 16 + l15;
                af[m] = *(const long*)(Ab + row * 128 + (koff ^ ((row & 7) << 4)));
            }
#pragma unroll
            for (int n = 0; n < 2; ++n) {
                int rowf = wc * 32 + n * 16 + l15;
                int off = rowf * 128 + (koff ^ ((rowf & 7) << 4));
                long b1 = *(const long*)(Bb + off);
                long b3 = *(const long*)(Bb + 8192 + off);
#pragma unroll
                for (int m = 0; m < 4; ++m) {
                    hacc[m][n] = __builtin_amdgcn_mfma_f32_16x16x32_fp8_fp8(af[m], b1, hacc[m][n], 0, 0, 0);
                    gacc[m][n] = __builtin_amdgcn_mfma_f32_16x16x32_fp8_fp8(af[m], b3, gacc[m][n], 0, 0, 0);
                }
            }
        }
        __builtin_amdgcn_s_setprio(0);
    };

    auto epilogueT = [&](const float b1v[2], const float b3v[2], int mstart_, int mlen_) {
#pragma unroll
        for (int m = 0; m < 4; ++m)
#pragma unroll
            for (int n = 0; n < 2; ++n)
#pragma unroll
                for (int j = 0; j < 4; ++j) {
                    float h = hacc[m][n][j] + b1v[n];
                    float gg = gacc[m][n][j] + b3v[n];
                    int row = wr * 64 + m * 16 + lk * 4 + j;
                    int col = wc * 32 + n * 16 + l15;
                    eplds[row * 64 + col] = f2fp8(siluf(h) * siluf(gg));
                }
        __syncthreads();
        int r = tid >> 1, cb = (tid & 1) * 32;
        if (r < mlen_) {
            unsigned char* gp = acts + (size_t)(mstart_ + r) * FF + fBase + cb;
            const unsigned char* lp = eplds + r * 64 + cb;
            *(uint4*)(gp)      = *(const uint4*)(lp);
            *(uint4*)(gp + 16) = *(const uint4*)(lp + 16);
        }
    };

#define G1_WAIT8 asm volatile("s_waitcnt vmcnt(8)" ::: "memory")
#define G1_BAR   __builtin_amdgcn_s_barrier()

    zacc();
    stage(0, a0, w1p0, w3p0, 0);
    stage(1, a0, w1p0, w3p0, 1);
    asm volatile("s_waitcnt vmcnt(0)" ::: "memory");
    __syncthreads();

    /*s0*/ computeStep(0); G1_BAR; stage(0, a0, w1p0, w3p0, 2);
    /*s1*/ G1_BAR; computeStep(1); G1_BAR; stage(1, a0, w1p0, w3p0, 3);
    /*s2*/ G1_WAIT8; G1_BAR; computeStep(0); G1_BAR; stage(0, a0, w1p0, w3p0, 4);
    /*s3*/ G1_WAIT8; G1_BAR; computeStep(1); G1_BAR; stage(1, a0, w1p0, w3p0, 5);
    /*s4*/ G1_WAIT8; G1_BAR; computeStep(0); G1_BAR; stage(0, a1, w1p1, w3p1, 0);
    /*s5*/ G1_WAIT8; G1_BAR; computeStep(1); G1_BAR; stage(1, a1, w1p1, w3p1, 1);

    epilogueT(tb1[0], tb3[0], mstart0, mlen0);
    asm volatile("s_waitcnt vmcnt(0)" ::: "memory");
    __syncthreads();

    if (have2) {
        zacc();
        /*s0*/ computeStep(0); G1_BAR; stage(0, a1, w1p1, w3p1, 2);
        /*s1*/ G1_BAR; computeStep(1); G1_BAR; stage(1, a1, w1p1, w3p1, 3);
        /*s2*/ G1_WAIT8; G1_BAR; computeStep(0); G1_BAR; stage(0, a1, w1p1, w3p1, 4);
        /*s3*/ G1_WAIT8; G1_BAR; computeStep(1); G1_BAR; stage(1, a1, w1p1, w3p1, 5);
        /*s4*/ G1_WAIT8; G1_BAR; computeStep(0); G1_BAR;
        /*s5*/ asm volatile("s_waitcnt vmcnt(0)" ::: "memory"); G1_BAR; computeStep(1); G1_BAR;
        epilogueT(tb1[1], tb3[1], mstart1, mlen1);
    }
#undef G1_WAIT8
#undef G1_BAR
}

// ---------------------------------------------------------------------------
// GEMM2 (fp8): 128x128 tile, split-K=2, BK=128 -> 12 steps. Unchanged.
// ---------------------------------------------------------------------------
__global__ __launch_bounds__(256, 2)
void gemm2_kernel(const unsigned char* __restrict__ acts,
                  const unsigned char* __restrict__ w2t,
                  const int* __restrict__ tme, const int* __restrict__ tmm,
                  const int* __restrict__ tml,
                  float* __restrict__ ffs) {
    int mt = blockIdx.y;
    int e = tme[mt];
    if (e < 0) return;
    int mstart = tmm[mt], mlen = tml[mt];
    int nBase = blockIdx.x * 128;
    int ksl = blockIdx.z;

    __shared__ char As[2][16384];
    __shared__ char Bs[2][16384];

    int tid = threadIdx.x;
    int lane = tid & 63, wv = tid >> 6;
    int wr = wv & 1, wc = wv >> 1;
    int l15 = lane & 15, lk = lane >> 4;
    int lrow = lane >> 3;
    int swl = (((lane & 7) ^ lrow) << 4);

    const char* ap = (const char*)acts;
    const char* w2p = (const char*)(w2t + (size_t)e * (size_t)D * FF);
    size_t aoff[4], boff[4];
#pragma unroll
    for (int i = 0; i < 4; ++i) {
        int r = (wv + 4 * i) * 8 + lrow;
        aoff[i] = (size_t)(mstart + r) * FF + swl;
        boff[i] = (size_t)(nBase + r) * FF + swl;
    }
    int kOff = ksl * (FF / 2);

    auto stage = [&](int buf, int ks) {
        int kb = kOff + ks * 128;
        char* ab = &As[buf][0];
        char* bb = &Bs[buf][0];
#pragma unroll
        for (int i = 0; i < 4; ++i) {
            gload16(ap + aoff[i] + kb, ab + (wv + 4 * i) * 1024);
            gload16(w2p + boff[i] + kb, bb + (wv + 4 * i) * 1024);
        }
    };

    f32x4 facc[4][4];
#pragma unroll
    for (int m = 0; m < 4; ++m)
#pragma unroll
        for (int n = 0; n < 4; ++n) facc[m][n] = f32x4{0.f, 0.f, 0.f, 0.f};

    stage(0, 0);
    stage(1, 1);
#pragma unroll 1
    for (int ks = 0; ks < 12; ++ks) {
        int cur = ks & 1;
        if (ks < 11) asm volatile("s_waitcnt vmcnt(8)" ::: "memory");
        else         asm volatile("s_waitcnt vmcnt(0)" ::: "memory");
        __builtin_amdgcn_s_barrier();
        const char* Ab = &As[cur][0];
        const char* Bb = &Bs[cur][0];
        __builtin_amdgcn_s_setprio(1);
#pragma unroll
        for (int ksub = 0; ksub < 4; ++ksub) {
            int koff = ksub * 32 + lk * 8;
            long af[4], bf[4];
#pragma unroll
            for (int m = 0; m < 4; ++m) {
                int row = wr * 64 + m * 16 + l15;
                af[m] = *(const long*)(Ab + row * 128 + (koff ^ ((row & 7) << 4)));
            }
#pragma unroll
            for (int n = 0; n < 4; ++n) {
                int row = wc * 64 + n * 16 + l15;
                bf[n] = *(const long*)(Bb + row * 128 + (koff ^ ((row & 7) << 4)));
            }
#pragma unroll
            for (int m = 0; m < 4; ++m)
#pragma unroll
                for (int n = 0; n < 4; ++n)
                    facc[m][n] = __builtin_amdgcn_mfma_f32_16x16x32_fp8_fp8(af[m], bf[n], facc[m][n], 0, 0, 0);
        }
        __builtin_amdgcn_s_setprio(0);
        __builtin_amdgcn_s_barrier();
        if (ks < 10) stage(cur, ks + 2);
    }

    float* op = ffs + (size_t)ksl * PSTRIDE;
#pragma unroll
    for (int m = 0; m < 4; ++m)
#pragma unroll
        for (int j = 0; j < 4; ++j) {
            int row = wr * 64 + m * 16 + lk * 4 + j;
            if (row < mlen) {
                float* gp = op + (size_t)(mstart + row) * D + nBase + wc * 64;
#pragma unroll
                for (int n = 0; n < 4; ++n)
                    gp[n * 16 + l15] = facc[m][n][j];
            }
        }
}

// ---------------------------------------------------------------------------
// Combine — unchanged
// ---------------------------------------------------------------------------
__global__ __launch_bounds__(256)
void combine_kernel(const float* __restrict__ x,
                    const float* __restrict__ ffs,
                    const int* __restrict__ e_arr,
                    const int* __restrict__ pos_of,
                    const float* __restrict__ s_arr,
                    const float* __restrict__ w2b,
                    const float* __restrict__ lng,
                    const float* __restrict__ lnb,
                    float* __restrict__ out) {
    int t = blockIdx.x;
    int tid = threadIdx.x;
    int p0 = pos_of[t * 2], p1 = pos_of[t * 2 + 1];
    int e0 = e_arr[t * 2], e1 = e_arr[t * 2 + 1];
    float sw0 = s_arr[t * 2], sw1 = s_arr[t * 2 + 1];
    __shared__ float red[4][4];

    float y0[3], y1[3];
    float s0 = 0.f, q0 = 0.f, s1 = 0.f, q1 = 0.f;
#pragma unroll
    for (int m = 0; m < 3; ++m) {
        int d = tid + 256 * m;
        float xv = x[(size_t)t * D + d];
        float f0 = ffs[(size_t)p0 * D + d] + ffs[PSTRIDE + (size_t)p0 * D + d] + w2b[e0 * D + d];
        float f1 = ffs[(size_t)p1 * D + d] + ffs[PSTRIDE + (size_t)p1 * D + d] + w2b[e1 * D + d];
        float a = xv + sw0 * f0;
        float bb = xv + sw1 * f1;
        y0[m] = a; y1[m] = bb;
        s0 += a; q0 += a * a;
        s1 += bb; q1 += bb * bb;
    }
    for (int off = 32; off; off >>= 1) {
        s0 += __shfl_xor(s0, off);
        q0 += __shfl_xor(q0, off);
        s1 += __shfl_xor(s1, off);
        q1 += __shfl_xor(q1, off);
    }
    int wv = tid >> 6, lane = tid & 63;
    if (lane == 0) { red[wv][0] = s0; red[wv][1] = q0; red[wv][2] = s1; red[wv][3] = q1; }
    __syncthreads();
    s0 = red[0][0] + red[1][0] + red[2][0] + red[3][0];
    q0 = red[0][1] + red[1][1] + red[2][1] + red[3][1];
    s1 = red[0][2] + red[1][2] + red[2][2] + red[3][2];
    q1 = red[0][3] + red[1][3] + red[2][3] + red[3][3];

    const float invD = 1.0f / (float)D;
    float mu0 = s0 * invD, var0 = q0 * invD - mu0 * mu0;
    float mu1 = s1 * invD, var1 = q1 * invD - mu1 * mu1;
    float r0 = rsqrtf(var0 + 1e-5f);
    float r1 = rsqrtf(var1 + 1e-5f);

#pragma unroll
    for (int m = 0; m < 3; ++m) {
        int d = tid + 256 * m;
        out[(size_t)t * D + d] =
            (y0[m] - mu0) * r0 * lng[e0 * D + d] + lnb[e0 * D + d] +
            (y1[m] - mu1) * r1 * lng[e1 * D + d] + lnb[e1 * D + d];
    }
}

// ---------------------------------------------------------------------------
extern "C" void kernel_launch(void* const* d_in, const int* in_sizes, int n_in,
                              void* d_out, int out_size, void* d_ws, size_t ws_size,
                              hipStream_t stream) {
    const float* x   = (const float*)d_in[0];
    const float* rw  = (const float*)d_in[1];
    const float* rb  = (const float*)d_in[2];
    const float* dgw = (const float*)d_in[3];
    const float* dgb = (const float*)d_in[4];
    const float* w1  = (const float*)d_in[5];
    const float* w1b = (const float*)d_in[6];
    const float* w2  = (const float*)d_in[7];
    const float* w2b = (const float*)d_in[8];
    const float* w3  = (const float*)d_in[9];
    const float* w3b = (const float*)d_in[10];
    const float* lng = (const float*)d_in[11];
    const float* lnb = (const float*)d_in[12];

    float* out = (float*)d_out;
    float* load_out = out + (size_t)T * D;

    char* w = (char*)d_ws;
    size_t off = 0;
    auto alloc = [&](size_t bytes) -> void* {
        void* p = w + off;
        off = (off + bytes + 255) & ~(size_t)255;
        return p;
    };
    int* e_arr    = (int*)alloc(NPOS * sizeof(int));
    int* a_tok    = (int*)alloc(NPOS * sizeof(int));
    int* pos_of   = (int*)alloc(NPOS * sizeof(int));
    float* s_arr  = (float*)alloc(NPOS * sizeof(float));
    int* tme      = (int*)alloc(MAXTILE * sizeof(int));
    int* tmm      = (int*)alloc(MAXTILE * sizeof(int));
    int* tml      = (int*)alloc(MAXTILE * sizeof(int));
    unsigned char* xb  = (unsigned char*)alloc((size_t)T * D);
    unsigned char* w1t = (unsigned char*)alloc((size_t)E * D * FF);
    unsigned char* w3t = (unsigned char*)alloc((size_t)E * D * FF);
    unsigned char* w2t = (unsigned char*)alloc((size_t)E * D * FF);
    unsigned char* acts = (unsigned char*)alloc((size_t)(NPOS + 128) * FF);
    float* ffs    = (float*)alloc(2 * PSTRIDE * sizeof(float));

    pre_kernel<<<2816, 256, 0, stream>>>(x, rw, rb, dgw, dgb, w1, w3,
                                         xb, e_arr, s_arr, w1t, w3t);
    scan_assign_kernel<<<1, 256, 0, stream>>>(e_arr, load_out, tme, tmm, tml,
                                              a_tok, pos_of);
    gemm1_w2t_kernel<<<2112, 256, 0, stream>>>(
        w2, w2t, xb, w1t, w1b, w3t, w3b, a_tok, tme, tmm, tml, acts);
    gemm2_kernel<<<dim3(D / 128, MAXTILE, 2), 256, 0, stream>>>(
        acts, w2t, tme, tmm, tml, ffs);
    combine_kernel<<<T, 256, 0, stream>>>(x, ffs, e_arr, pos_of, s_arr, w2b, lng, lnb, out);
}

// Round 16
// 141.763 us; speedup vs baseline: 9.5695x; 1.0575x over previous
//
#include <hip/hip_runtime.h>
#include <math.h>

#define T 2048
#define D 768
#define E 8
#define FF 3072
#define NPOS (2 * T)
#define MAXTILE 40
#define PSTRIDE ((size_t)(NPOS + 128) * D)

using f32x4 = __attribute__((ext_vector_type(4))) float;

template<bool HI>
__device__ __forceinline__ unsigned f2fp8pk(float a, float b, unsigned old) {
    return __builtin_amdgcn_cvt_pk_fp8_f32(a, b, (int)old, HI);
}
__device__ __forceinline__ unsigned char f2fp8(float f) {
    return (unsigned char)(__builtin_amdgcn_cvt_pk_fp8_f32(f, 0.f, 0, false) & 0xff);
}
__device__ __forceinline__ float siluf(float v) {
    return v / (1.0f + __expf(-v));
}
__device__ __forceinline__ void gload16(const void* g, void* l) {
    __builtin_amdgcn_global_load_lds(
        (const __attribute__((address_space(1))) void*)g,
        (__attribute__((address_space(3))) void*)l, 16, 0, 0);
}

// ---------------------------------------------------------------------------
// transpose128 (R12-verified, best-measured): 128x128 f32 tile -> fp8
// transposed via gload_lds staging (full MLP), convert+pack, 128B-line stores.
// ---------------------------------------------------------------------------
__device__ __forceinline__ void transpose128(const float* __restrict__ in,
                                             unsigned char* __restrict__ out,
                                             int C, int Rb, int r0, int c0,
                                             char* smem, int tid) {
    int wv = tid >> 6, lane = tid & 63;
    size_t rowB = (size_t)C * 4;
    const char* inb = (const char*)in + (size_t)r0 * rowB + (size_t)c0 * 4;
    const char* src_lane = inb + (size_t)(lane >> 5) * rowB + (lane & 31) * 16;
#pragma unroll
    for (int i = 0; i < 16; ++i) {
        int rpair = i * 4 + wv;
        gload16(src_lane + (size_t)(2 * rpair) * rowB, smem + rpair * 1024);
    }
    asm volatile("s_waitcnt vmcnt(0)" ::: "memory");
    __syncthreads();

    const float* fin = (const float*)smem;
    int cb = (tid & 31) * 4;
    int rgb = tid >> 5;
    unsigned pk[4][4];
#pragma unroll
    for (int p = 0; p < 4; ++p) {
        int rb = (rgb + 8 * p) * 4;
        float4 q0 = *(const float4*)(fin + (rb + 0) * 128 + cb);
        float4 q1 = *(const float4*)(fin + (rb + 1) * 128 + cb);
        float4 q2 = *(const float4*)(fin + (rb + 2) * 128 + cb);
        float4 q3 = *(const float4*)(fin + (rb + 3) * 128 + cb);
        unsigned w;
        w = f2fp8pk<false>(q0.x, q1.x, 0); w = f2fp8pk<true>(q2.x, q3.x, w); pk[p][0] = w;
        w = f2fp8pk<false>(q0.y, q1.y, 0); w = f2fp8pk<true>(q2.y, q3.y, w); pk[p][1] = w;
        w = f2fp8pk<false>(q0.z, q1.z, 0); w = f2fp8pk<true>(q2.z, q3.z, w); pk[p][2] = w;
        w = f2fp8pk<false>(q0.w, q1.w, 0); w = f2fp8pk<true>(q2.w, q3.w, w); pk[p][3] = w;
    }
    __syncthreads();
    unsigned* po = (unsigned*)smem;    // [128 cols][33 words]
#pragma unroll
    for (int p = 0; p < 4; ++p) {
        int rg = rgb + 8 * p;
#pragma unroll
        for (int j = 0; j < 4; ++j)
            po[(cb + j) * 33 + rg] = pk[p][j];
    }
    __syncthreads();
#pragma unroll
    for (int p = 0; p < 4; ++p) {
        int c = (tid >> 3) + 32 * p;
        int gs = tid & 7;
        const unsigned* bp = &po[c * 33 + gs * 4];
        uint4 val;
        val.x = bp[0]; val.y = bp[1]; val.z = bp[2]; val.w = bp[3];
        *(uint4*)(out + (size_t)(c0 + c) * Rb + r0 + gs * 16) = val;
    }
}

// ---------------------------------------------------------------------------
// Dispatch 1: router (512) + w1/w3 transpose (2304), interleaved 2:9
// (measured WIN in R14: router hides under transposes)
// ---------------------------------------------------------------------------
__global__ __launch_bounds__(256, 2)
void pre_kernel(const float* __restrict__ x,
                const float* __restrict__ rw, const float* __restrict__ rbias,
                const float* __restrict__ dgw, const float* __restrict__ dgb,
                const float* __restrict__ w1, const float* __restrict__ w3,
                unsigned char* __restrict__ xb,
                int* __restrict__ e_arr, float* __restrict__ s_arr,
                unsigned char* __restrict__ w1t, unsigned char* __restrict__ w3t) {
    __shared__ __align__(16) char smem[73728];
    int bid = blockIdx.x;
    int tid = threadIdx.x;
    int grp = bid / 11, rem = bid % 11;

    if (rem >= 2) {
        // ---- w1/w3 transpose flavor ----
        int idx = grp * 9 + (rem - 2);    // 0..2303
        int z = idx / 144;
        int tile = idx % 144;
        int r0 = (tile % 6) * 128;
        int c0 = (tile / 6) * 128;
        const float* in;
        unsigned char* outp;
        if (z < 8) { in = w1 + (size_t)z * D * FF; outp = w1t + (size_t)z * D * FF; }
        else       { in = w3 + (size_t)(z - 8) * D * FF; outp = w3t + (size_t)(z - 8) * D * FF; }
        transpose128(in, outp, FF, D, r0, c0, smem, tid);
        return;
    }

    // ---- router flavor ----
    int rblk = grp * 2 + rem;             // 0..511
    int lane = tid & 63;
    int wv = tid >> 6;
    int t = rblk * 4 + wv;

    float lg[E], dl[E];
#pragma unroll
    for (int e = 0; e < E; ++e) { lg[e] = 0.f; dl[e] = 0.f; }

    const float* xt = x + (size_t)t * D;
    unsigned char* xbt = xb + (size_t)t * D;
#pragma unroll
    for (int i = 0; i < D / 64; ++i) {
        int d = lane + 64 * i;
        float xv = xt[d];
        xbt[d] = f2fp8(xv);
#pragma unroll
        for (int e = 0; e < E; ++e) {
            lg[e] = fmaf(xv, rw[d * E + e], lg[e]);
            dl[e] = fmaf(xv, dgw[e * D + d], dl[e]);
        }
    }
#pragma unroll
    for (int e = 0; e < E; ++e) {
        for (int off = 32; off; off >>= 1) {
            lg[e] += __shfl_xor(lg[e], off);
            dl[e] += __shfl_xor(dl[e], off);
        }
    }
    if (lane == 0) {
        float p[E];
        float m = -1e30f;
#pragma unroll
        for (int e = 0; e < E; ++e) { lg[e] += rbias[e]; m = fmaxf(m, lg[e]); }
        float s = 0.f;
#pragma unroll
        for (int e = 0; e < E; ++e) { p[e] = __expf(lg[e] - m); s += p[e]; }
        float inv = 1.0f / s;
#pragma unroll
        for (int e = 0; e < E; ++e) p[e] *= inv;

        int i0 = 0; float b0 = p[0];
#pragma unroll
        for (int e = 1; e < E; ++e) if (p[e] > b0) { b0 = p[e]; i0 = e; }
        int i1 = -1; float b1 = -1.0f;
#pragma unroll
        for (int e = 0; e < E; ++e) if (e != i0 && p[e] > b1) { b1 = p[e]; i1 = e; }

        float eb = __expf(b1 - b0);
        float w0 = 1.0f / (1.0f + eb);
        float w1v = eb / (1.0f + eb);

        float dg0 = 1.0f / (1.0f + __expf(-(dl[i0] + dgb[i0])));
        float dg1 = 1.0f / (1.0f + __expf(-(dl[i1] + dgb[i1])));

        e_arr[t * 2 + 0] = i0;
        e_arr[t * 2 + 1] = i1;
        s_arr[t * 2 + 0] = dg0 * w0;
        s_arr[t * 2 + 1] = dg1 * w1v;
    }
}

// ---------------------------------------------------------------------------
// Dispatch 2: scan+assign (counts in-LDS)
// ---------------------------------------------------------------------------
__global__ __launch_bounds__(256)
void scan_assign_kernel(const int* __restrict__ e_arr,
                        float* __restrict__ load_out,
                        int* __restrict__ tme, int* __restrict__ tmm,
                        int* __restrict__ tml,
                        int* __restrict__ a_tok,
                        int* __restrict__ pos_of) {
    __shared__ int lcnt[E];
    __shared__ int lcur[E];
    int tid = threadIdx.x;
    if (tid < E) lcnt[tid] = 0;
    __syncthreads();
    for (int t = tid; t < T; t += 256) {
        atomicAdd(&lcnt[e_arr[t * 2]], 1);
        atomicAdd(&lcnt[e_arr[t * 2 + 1]], 1);
    }
    __syncthreads();
    if (tid == 0) {
        int b = 0, nt = 0;
        for (int e = 0; e < E; ++e) {
            int c = lcnt[e];
            lcur[e] = b;
            load_out[e] = (float)c;
            for (int m = 0; m < c; m += 128) {
                tme[nt] = e;
                tmm[nt] = b + m;
                tml[nt] = (c - m < 128) ? (c - m) : 128;
                ++nt;
            }
            b += c;
        }
        for (; nt < MAXTILE; ++nt) tme[nt] = -1;
    }
    __syncthreads();
    for (int t = tid; t < T; t += 256) {
#pragma unroll
        for (int s = 0; s < 2; ++s) {
            int e = e_arr[t * 2 + s];
            int pos = atomicAdd(&lcur[e], 1);
            a_tok[pos] = t;
            pos_of[t * 2 + s] = pos;
        }
    }
}

// ---------------------------------------------------------------------------
// Dispatch 3: GEMM1 blocks [0,960) FIRST + w2 transpose blocks [960, 2112)
// (block-ordered: measured best in R12 — w2t's f32 streaming otherwise
// evicts gemm1's L2-resident fp8 weights)
// ---------------------------------------------------------------------------
__global__ __launch_bounds__(256, 2)
void gemm1_w2t_kernel(const float* __restrict__ w2, unsigned char* __restrict__ w2t,
                      const unsigned char* __restrict__ xb,
                      const unsigned char* __restrict__ w1t, const float* __restrict__ w1b,
                      const unsigned char* __restrict__ w3t, const float* __restrict__ w3b,
                      const int* __restrict__ a_tok,
                      const int* __restrict__ tme, const int* __restrict__ tmm,
                      const int* __restrict__ tml,
                      unsigned char* __restrict__ acts) {
    __shared__ __align__(16) char smem[73728];
    int bid = blockIdx.x;
    int tid = threadIdx.x;

    if (bid >= 960) {   // ---- w2 transpose flavor ----
        int idx = bid - 960;
        int z = idx / 144;
        int tile = idx % 144;
        int r0 = (tile % 24) * 128;
        int c0 = (tile / 24) * 128;
        transpose128(w2 + (size_t)z * FF * D, w2t + (size_t)z * FF * D,
                     D, FF, r0, c0, smem, tid);
        return;
    }

    // ---- gemm1 persistent flavor ----
    int slot = bid / 48;
    int fBase = (bid % 48) * 64;
    int mt0 = slot * 2;
    int e0 = tme[mt0];
    if (e0 < 0) return;
    int e1 = tme[mt0 + 1];
    bool have2 = (e1 >= 0);
    int mstart0 = tmm[mt0], mlen0 = tml[mt0];
    int mstart1 = have2 ? tmm[mt0 + 1] : mstart0;
    int mlen1   = have2 ? tml[mt0 + 1] : mlen0;
    if (!have2) e1 = e0;

    char* As = smem;              // 2 x 16KB
    char* Bs = smem + 32768;      // 2 x 16KB
    unsigned char* eplds = (unsigned char*)(smem + 65536);  // 8KB

    int lane = tid & 63, wv = tid >> 6;
    int wr = wv & 1, wc = wv >> 1;
    int l15 = lane & 15, lk = lane >> 4;
    int lrow = lane >> 3;
    int swl = (((lane & 7) ^ lrow) << 4);

    const char* xbp = (const char*)xb;
    const char* w1p0 = (const char*)(w1t + (size_t)e0 * FF * D);
    const char* w3p0 = (const char*)(w3t + (size_t)e0 * FF * D);
    const char* w1p1 = (const char*)(w1t + (size_t)e1 * FF * D);
    const char* w3p1 = (const char*)(w3t + (size_t)e1 * FF * D);

    size_t boff[2];
#pragma unroll
    for (int i = 0; i < 2; ++i) {
        int f = (wv + 4 * i) * 8 + lrow;
        boff[i] = (size_t)(fBase + f) * D + swl;
    }

    size_t a0[4], a1[4];
#pragma unroll
    for (int i = 0; i < 4; ++i) {
        int r = (wv + 4 * i) * 8 + lrow;
        int rr0 = r < mlen0 ? r : mlen0 - 1;
        int rr1 = r < mlen1 ? r : mlen1 - 1;
        a0[i] = (size_t)a_tok[mstart0 + rr0] * D + swl;
        a1[i] = (size_t)a_tok[mstart1 + rr1] * D + swl;
    }
    float tb1[2][2], tb3[2][2];
#pragma unroll
    for (int n = 0; n < 2; ++n) {
        int f = fBase + wc * 32 + n * 16 + l15;
        tb1[0][n] = w1b[e0 * FF + f];
        tb3[0][n] = w3b[e0 * FF + f];
        tb1[1][n] = w1b[e1 * FF + f];
        tb3[1][n] = w3b[e1 * FF + f];
    }

    auto stage = [&](int buf, const size_t* ao, const char* w1p_, const char* w3p_, int ks) {
        int kb = ks * 128;
        char* ab = As + buf * 16384;
        char* bb = Bs + buf * 16384;
#pragma unroll
        for (int i = 0; i < 4; ++i)
            gload16(xbp + ao[i] + kb, ab + (wv + 4 * i) * 1024);
#pragma unroll
        for (int i = 0; i < 2; ++i) {
            gload16(w1p_ + boff[i] + kb, bb + (wv + 4 * i) * 1024);
            gload16(w3p_ + boff[i] + kb, bb + 8192 + (wv + 4 * i) * 1024);
        }
    };

    f32x4 hacc[4][2], gacc[4][2];
    auto zacc = [&]() {
#pragma unroll
        for (int m = 0; m < 4; ++m)
#pragma unroll
            for (int n = 0; n < 2; ++n) {
                hacc[m][n] = f32x4{0.f, 0.f, 0.f, 0.f};
                gacc[m][n] = f32x4{0.f, 0.f, 0.f, 0.f};
            }
    };

    auto computeStep = [&](int buf) {
        const char* Ab = As + buf * 16384;
        const char* Bb = Bs + buf * 16384;
        __builtin_amdgcn_s_setprio(1);
#pragma unroll
        for (int ksub = 0; ksub < 4; ++ksub) {
            int koff = ksub * 32 + lk * 8;
            long af[4];
#pragma unroll
            for (int m = 0; m < 4; ++m) {
                int row = wr * 64 + m * 16 + l15;
                af[m] = *(const long*)(Ab + row * 128 + (koff ^ ((row & 7) << 4)));
            }
#pragma unroll
            for (int n = 0; n < 2; ++n) {
                int rowf = wc * 32 + n * 16 + l15;
                int off = rowf * 128 + (koff ^ ((rowf & 7) << 4));
                long b1 = *(const long*)(Bb + off);
                long b3 = *(const long*)(Bb + 8192 + off);
#pragma unroll
                for (int m = 0; m < 4; ++m) {
                    hacc[m][n] = __builtin_amdgcn_mfma_f32_16x16x32_fp8_fp8(af[m], b1, hacc[m][n], 0, 0, 0);
                    gacc[m][n] = __builtin_amdgcn_mfma_f32_16x16x32_fp8_fp8(af[m], b3, gacc[m][n], 0, 0, 0);
                }
            }
        }
        __builtin_amdgcn_s_setprio(0);
    };

    auto epilogueT = [&](const float b1v[2], const float b3v[2], int mstart_, int mlen_) {
#pragma unroll
        for (int m = 0; m < 4; ++m)
#pragma unroll
            for (int n = 0; n < 2; ++n)
#pragma unroll
                for (int j = 0; j < 4; ++j) {
                    float h = hacc[m][n][j] + b1v[n];
                    float gg = gacc[m][n][j] + b3v[n];
                    int row = wr * 64 + m * 16 + lk * 4 + j;
                    int col = wc * 32 + n * 16 + l15;
                    eplds[row * 64 + col] = f2fp8(siluf(h) * siluf(gg));
                }
        __syncthreads();
        int r = tid >> 1, cb = (tid & 1) * 32;
        if (r < mlen_) {
            unsigned char* gp = acts + (size_t)(mstart_ + r) * FF + fBase + cb;
            const unsigned char* lp = eplds + r * 64 + cb;
            *(uint4*)(gp)      = *(const uint4*)(lp);
            *(uint4*)(gp + 16) = *(const uint4*)(lp + 16);
        }
    };

#define G1_WAIT8 asm volatile("s_waitcnt vmcnt(8)" ::: "memory")
#define G1_BAR   __builtin_amdgcn_s_barrier()

    zacc();
    stage(0, a0, w1p0, w3p0, 0);
    stage(1, a0, w1p0, w3p0, 1);
    asm volatile("s_waitcnt vmcnt(0)" ::: "memory");
    __syncthreads();

    /*s0*/ computeStep(0); G1_BAR; stage(0, a0, w1p0, w3p0, 2);
    /*s1*/ G1_BAR; computeStep(1); G1_BAR; stage(1, a0, w1p0, w3p0, 3);
    /*s2*/ G1_WAIT8; G1_BAR; computeStep(0); G1_BAR; stage(0, a0, w1p0, w3p0, 4);
    /*s3*/ G1_WAIT8; G1_BAR; computeStep(1); G1_BAR; stage(1, a0, w1p0, w3p0, 5);
    /*s4*/ G1_WAIT8; G1_BAR; computeStep(0); G1_BAR; stage(0, a1, w1p1, w3p1, 0);
    /*s5*/ G1_WAIT8; G1_BAR; computeStep(1); G1_BAR; stage(1, a1, w1p1, w3p1, 1);

    epilogueT(tb1[0], tb3[0], mstart0, mlen0);
    asm volatile("s_waitcnt vmcnt(0)" ::: "memory");
    __syncthreads();

    if (have2) {
        zacc();
        /*s0*/ computeStep(0); G1_BAR; stage(0, a1, w1p1, w3p1, 2);
        /*s1*/ G1_BAR; computeStep(1); G1_BAR; stage(1, a1, w1p1, w3p1, 3);
        /*s2*/ G1_WAIT8; G1_BAR; computeStep(0); G1_BAR; stage(0, a1, w1p1, w3p1, 4);
        /*s3*/ G1_WAIT8; G1_BAR; computeStep(1); G1_BAR; stage(1, a1, w1p1, w3p1, 5);
        /*s4*/ G1_WAIT8; G1_BAR; computeStep(0); G1_BAR;
        /*s5*/ asm volatile("s_waitcnt vmcnt(0)" ::: "memory"); G1_BAR; computeStep(1); G1_BAR;
        epilogueT(tb1[1], tb3[1], mstart1, mlen1);
    }
#undef G1_WAIT8
#undef G1_BAR
}

// ---------------------------------------------------------------------------
// GEMM2 (fp8): 128x128 tile, split-K=2, BK=128 -> 12 steps. Unchanged.
// ---------------------------------------------------------------------------
__global__ __launch_bounds__(256, 2)
void gemm2_kernel(const unsigned char* __restrict__ acts,
                  const unsigned char* __restrict__ w2t,
                  const int* __restrict__ tme, const int* __restrict__ tmm,
                  const int* __restrict__ tml,
                  float* __restrict__ ffs) {
    int mt = blockIdx.y;
    int e = tme[mt];
    if (e < 0) return;
    int mstart = tmm[mt], mlen = tml[mt];
    int nBase = blockIdx.x * 128;
    int ksl = blockIdx.z;

    __shared__ char As[2][16384];
    __shared__ char Bs[2][16384];

    int tid = threadIdx.x;
    int lane = tid & 63, wv = tid >> 6;
    int wr = wv & 1, wc = wv >> 1;
    int l15 = lane & 15, lk = lane >> 4;
    int lrow = lane >> 3;
    int swl = (((lane & 7) ^ lrow) << 4);

    const char* ap = (const char*)acts;
    const char* w2p = (const char*)(w2t + (size_t)e * (size_t)D * FF);
    size_t aoff[4], boff[4];
#pragma unroll
    for (int i = 0; i < 4; ++i) {
        int r = (wv + 4 * i) * 8 + lrow;
        aoff[i] = (size_t)(mstart + r) * FF + swl;
        boff[i] = (size_t)(nBase + r) * FF + swl;
    }
    int kOff = ksl * (FF / 2);

    auto stage = [&](int buf, int ks) {
        int kb = kOff + ks * 128;
        char* ab = &As[buf][0];
        char* bb = &Bs[buf][0];
#pragma unroll
        for (int i = 0; i < 4; ++i) {
            gload16(ap + aoff[i] + kb, ab + (wv + 4 * i) * 1024);
            gload16(w2p + boff[i] + kb, bb + (wv + 4 * i) * 1024);
        }
    };

    f32x4 facc[4][4];
#pragma unroll
    for (int m = 0; m < 4; ++m)
#pragma unroll
        for (int n = 0; n < 4; ++n) facc[m][n] = f32x4{0.f, 0.f, 0.f, 0.f};

    stage(0, 0);
    stage(1, 1);
#pragma unroll 1
    for (int ks = 0; ks < 12; ++ks) {
        int cur = ks & 1;
        if (ks < 11) asm volatile("s_waitcnt vmcnt(8)" ::: "memory");
        else         asm volatile("s_waitcnt vmcnt(0)" ::: "memory");
        __builtin_amdgcn_s_barrier();
        const char* Ab = &As[cur][0];
        const char* Bb = &Bs[cur][0];
        __builtin_amdgcn_s_setprio(1);
#pragma unroll
        for (int ksub = 0; ksub < 4; ++ksub) {
            int koff = ksub * 32 + lk * 8;
            long af[4], bf[4];
#pragma unroll
            for (int m = 0; m < 4; ++m) {
                int row = wr * 64 + m * 16 + l15;
                af[m] = *(const long*)(Ab + row * 128 + (koff ^ ((row & 7) << 4)));
            }
#pragma unroll
            for (int n = 0; n < 4; ++n) {
                int row = wc * 64 + n * 16 + l15;
                bf[n] = *(const long*)(Bb + row * 128 + (koff ^ ((row & 7) << 4)));
            }
#pragma unroll
            for (int m = 0; m < 4; ++m)
#pragma unroll
                for (int n = 0; n < 4; ++n)
                    facc[m][n] = __builtin_amdgcn_mfma_f32_16x16x32_fp8_fp8(af[m], bf[n], facc[m][n], 0, 0, 0);
        }
        __builtin_amdgcn_s_setprio(0);
        __builtin_amdgcn_s_barrier();
        if (ks < 10) stage(cur, ks + 2);
    }

    float* op = ffs + (size_t)ksl * PSTRIDE;
#pragma unroll
    for (int m = 0; m < 4; ++m)
#pragma unroll
        for (int j = 0; j < 4; ++j) {
            int row = wr * 64 + m * 16 + lk * 4 + j;
            if (row < mlen) {
                float* gp = op + (size_t)(mstart + row) * D + nBase + wc * 64;
#pragma unroll
                for (int n = 0; n < 4; ++n)
                    gp[n * 16 + l15] = facc[m][n][j];
            }
        }
}

// ---------------------------------------------------------------------------
// Combine — unchanged
// ---------------------------------------------------------------------------
__global__ __launch_bounds__(256)
void combine_kernel(const float* __restrict__ x,
                    const float* __restrict__ ffs,
                    const int* __restrict__ e_arr,
                    const int* __restrict__ pos_of,
                    const float* __restrict__ s_arr,
                    const float* __restrict__ w2b,
                    const float* __restrict__ lng,
                    const float* __restrict__ lnb,
                    float* __restrict__ out) {
    int t = blockIdx.x;
    int tid = threadIdx.x;
    int p0 = pos_of[t * 2], p1 = pos_of[t * 2 + 1];
    int e0 = e_arr[t * 2], e1 = e_arr[t * 2 + 1];
    float sw0 = s_arr[t * 2], sw1 = s_arr[t * 2 + 1];
    __shared__ float red[4][4];

    float y0[3], y1[3];
    float s0 = 0.f, q0 = 0.f, s1 = 0.f, q1 = 0.f;
#pragma unroll
    for (int m = 0; m < 3; ++m) {
        int d = tid + 256 * m;
        float xv = x[(size_t)t * D + d];
        float f0 = ffs[(size_t)p0 * D + d] + ffs[PSTRIDE + (size_t)p0 * D + d] + w2b[e0 * D + d];
        float f1 = ffs[(size_t)p1 * D + d] + ffs[PSTRIDE + (size_t)p1 * D + d] + w2b[e1 * D + d];
        float a = xv + sw0 * f0;
        float bb = xv + sw1 * f1;
        y0[m] = a; y1[m] = bb;
        s0 += a; q0 += a * a;
        s1 += bb; q1 += bb * bb;
    }
    for (int off = 32; off; off >>= 1) {
        s0 += __shfl_xor(s0, off);
        q0 += __shfl_xor(q0, off);
        s1 += __shfl_xor(s1, off);
        q1 += __shfl_xor(q1, off);
    }
    int wv = tid >> 6, lane = tid & 63;
    if (lane == 0) { red[wv][0] = s0; red[wv][1] = q0; red[wv][2] = s1; red[wv][3] = q1; }
    __syncthreads();
    s0 = red[0][0] + red[1][0] + red[2][0] + red[3][0];
    q0 = red[0][1] + red[1][1] + red[2][1] + red[3][1];
    s1 = red[0][2] + red[1][2] + red[2][2] + red[3][2];
    q1 = red[0][3] + red[1][3] + red[2][3] + red[3][3];

    const float invD = 1.0f / (float)D;
    float mu0 = s0 * invD, var0 = q0 * invD - mu0 * mu0;
    float mu1 = s1 * invD, var1 = q1 * invD - mu1 * mu1;
    float r0 = rsqrtf(var0 + 1e-5f);
    float r1 = rsqrtf(var1 + 1e-5f);

#pragma unroll
    for (int m = 0; m < 3; ++m) {
        int d = tid + 256 * m;
        out[(size_t)t * D + d] =
            (y0[m] - mu0) * r0 * lng[e0 * D + d] + lnb[e0 * D + d] +
            (y1[m] - mu1) * r1 * lng[e1 * D + d] + lnb[e1 * D + d];
    }
}

// ---------------------------------------------------------------------------
extern "C" void kernel_launch(void* const* d_in, const int* in_sizes, int n_in,
                              void* d_out, int out_size, void* d_ws, size_t ws_size,
                              hipStream_t stream) {
    const float* x   = (const float*)d_in[0];
    const float* rw  = (const float*)d_in[1];
    const float* rb  = (const float*)d_in[2];
    const float* dgw = (const float*)d_in[3];
    const float* dgb = (const float*)d_in[4];
    const float* w1  = (const float*)d_in[5];
    const float* w1b = (const float*)d_in[6];
    const float* w2  = (const float*)d_in[7];
    const float* w2b = (const float*)d_in[8];
    const float* w3  = (const float*)d_in[9];
    const float* w3b = (const float*)d_in[10];
    const float* lng = (const float*)d_in[11];
    const float* lnb = (const float*)d_in[12];

    float* out = (float*)d_out;
    float* load_out = out + (size_t)T * D;

    char* w = (char*)d_ws;
    size_t off = 0;
    auto alloc = [&](size_t bytes) -> void* {
        void* p = w + off;
        off = (off + bytes + 255) & ~(size_t)255;
        return p;
    };
    int* e_arr    = (int*)alloc(NPOS * sizeof(int));
    int* a_tok    = (int*)alloc(NPOS * sizeof(int));
    int* pos_of   = (int*)alloc(NPOS * sizeof(int));
    float* s_arr  = (float*)alloc(NPOS * sizeof(float));
    int* tme      = (int*)alloc(MAXTILE * sizeof(int));
    int* tmm      = (int*)alloc(MAXTILE * sizeof(int));
    int* tml      = (int*)alloc(MAXTILE * sizeof(int));
    unsigned char* xb  = (unsigned char*)alloc((size_t)T * D);
    unsigned char* w1t = (unsigned char*)alloc((size_t)E * D * FF);
    unsigned char* w3t = (unsigned char*)alloc((size_t)E * D * FF);
    unsigned char* w2t = (unsigned char*)alloc((size_t)E * D * FF);
    unsigned char* acts = (unsigned char*)alloc((size_t)(NPOS + 128) * FF);
    float* ffs    = (float*)alloc(2 * PSTRIDE * sizeof(float));

    pre_kernel<<<2816, 256, 0, stream>>>(x, rw, rb, dgw, dgb, w1, w3,
                                         xb, e_arr, s_arr, w1t, w3t);
    scan_assign_kernel<<<1, 256, 0, stream>>>(e_arr, load_out, tme, tmm, tml,
                                              a_tok, pos_of);
    gemm1_w2t_kernel<<<2112, 256, 0, stream>>>(
        w2, w2t, xb, w1t, w1b, w3t, w3b, a_tok, tme, tmm, tml, acts);
    gemm2_kernel<<<dim3(D / 128, MAXTILE, 2), 256, 0, stream>>>(
        acts, w2t, tme, tmm, tml, ffs);
    combine_kernel<<<T, 256, 0, stream>>>(x, ffs, e_arr, pos_of, s_arr, w2b, lng, lnb, out);
}